// Round 15
// baseline (11625.045 us; speedup 1.0000x reference)
//
#include <hip/hip_runtime.h>
#include <hip/hip_bf16.h>
#include <cstdint>

// ---------------------------------------------------------------------------
// B=32, L=2048, E=256, H=128, C=128. Scan steps j=0..2046 (t=j+1).
// R15: speculative 6-candidate scan. R14 proved the step is structure-bound
// (bf16 weights -2%; R8 resident weights 0%): the serial sampler + LSTM sit
// on the critical path. Since idx has only 6 outcomes, compute LSTM for ALL
// 6 candidates (P2a) and candidate hid-dots hhc[k]=Wp1part·h2c[k] (P2b);
// the sampler (P1, wave0) then needs only hhc[idx_prev] and runs fully
// overlapped with the big gate-dot ghh (waves 1-7). All dot trees / LSTM /
// sampler expressions verbatim R14 bf16 (absmax 0.0 lineage).
// ---------------------------------------------------------------------------
static constexpr int BB   = 32;
static constexpr int LQ   = 2048;
static constexpr int NSTP = 2047;
static constexpr int EE   = 256;

// scan LDS byte offsets (static 50KB union; GEMM branch uses first 8.5KB)
static constexpr int bEXF  = 0;                  // 2*3840*4 = 30720
static constexpr int bHHC  = 30720;              // 6*128*4  = 3072
static constexpr int bH2C  = 33792;              // 2*6*144*4= 6912 (padded rows)
static constexpr int bC2C  = 40704;              // 2*6*128*4= 6144
static constexpr int bGHH  = 46848;              // 512*4    = 2048
static constexpr int bSCV  = 48896;              // 32
static constexpr int bWP2  = 48928;              // 512
static constexpr int bGUM  = 49440;              // 64
static constexpr int bMSK  = 49504;              // 64
static constexpr int bIDXP = 49568;              // 8
static constexpr int bIDXB = 49576;              // 448
static constexpr int kSmem = 50048;
static constexpr int CSMAX = 448;

__device__ __forceinline__ void bar_lds() {
  asm volatile("s_waitcnt lgkmcnt(0)\n\ts_barrier" ::: "memory");
}

__device__ __forceinline__ float bfl(uint32_t u) {
  return __uint_as_float(u << 16);
}
__device__ __forceinline__ float bfh(uint32_t u) {
  return __uint_as_float(u & 0xffff0000u);
}
__device__ __forceinline__ unsigned short f2bf(float f) {
  uint32_t u = __float_as_uint(f);
  uint32_t r = (u + 0x7fffu + ((u >> 16) & 1u)) >> 16;
  return (unsigned short)r;
}

// ---------------- Threefry-2x32 (JAX-compatible, verified R3-R14) ----------
__device__ __forceinline__ uint32_t rotl32(uint32_t x, int d) {
  return (x << d) | (x >> (32 - d));
}
__device__ __forceinline__ void tf2x32(uint32_t k0, uint32_t k1,
                                       uint32_t x0, uint32_t x1,
                                       uint32_t& o0, uint32_t& o1) {
  uint32_t ks2 = k0 ^ k1 ^ 0x1BD11BDAu;
  x0 += k0; x1 += k1;
  x0+=x1; x1=rotl32(x1,13); x1^=x0;  x0+=x1; x1=rotl32(x1,15); x1^=x0;
  x0+=x1; x1=rotl32(x1,26); x1^=x0;  x0+=x1; x1=rotl32(x1, 6); x1^=x0;
  x0+=k1; x1+=ks2+1u;
  x0+=x1; x1=rotl32(x1,17); x1^=x0;  x0+=x1; x1=rotl32(x1,29); x1^=x0;
  x0+=x1; x1=rotl32(x1,16); x1^=x0;  x0+=x1; x1=rotl32(x1,24); x1^=x0;
  x0+=ks2; x1+=k0+2u;
  x0+=x1; x1=rotl32(x1,13); x1^=x0;  x0+=x1; x1=rotl32(x1,15); x1^=x0;
  x0+=x1; x1=rotl32(x1,26); x1^=x0;  x0+=x1; x1=rotl32(x1, 6); x1^=x0;
  x0+=k0; x1+=k1+3u;
  x0+=x1; x1=rotl32(x1,17); x1^=x0;  x0+=x1; x1=rotl32(x1,29); x1^=x0;
  x0+=x1; x1=rotl32(x1,16); x1^=x0;  x0+=x1; x1=rotl32(x1,24); x1^=x0;
  x0+=k1; x1+=ks2+4u;
  x0+=x1; x1=rotl32(x1,13); x1^=x0;  x0+=x1; x1=rotl32(x1,15); x1^=x0;
  x0+=x1; x1=rotl32(x1,26); x1^=x0;  x0+=x1; x1=rotl32(x1, 6); x1^=x0;
  x0+=ks2; x1+=k0+5u;
  o0 = x0; o1 = x1;
}

__device__ __forceinline__ float sigm(float x) { return 1.0f / (1.0f + expf(-x)); }

// ---------------- prep: bf16 weights, Wcomb/cbias --------------------------
__global__ void prep_kernel(const float* __restrict__ Wp1,
                            const float* __restrict__ bp1,
                            const float* __restrict__ Wih,
                            const float* __restrict__ Whh,
                            const float* __restrict__ bih,
                            const float* __restrict__ bhh,
                            float* __restrict__ Wcomb,
                            float* __restrict__ cbias,
                            unsigned short* __restrict__ WhcH,
                            unsigned short* __restrict__ Wp1H) {
  int tid = blockIdx.x * blockDim.x + threadIdx.x;
  int nt  = gridDim.x * blockDim.x;
  for (int p = tid; p < 512 * 128; p += nt) {
    int g = p >> 7, e = p & 127;
    WhcH[p] = f2bf(Wih[g * 256 + 128 + e] + Whh[p]);
  }
  for (int p = tid; p < 128 * 128; p += nt) {
    int r = p >> 7, e = p & 127;
    Wp1H[p] = f2bf(Wp1[r * 256 + 128 + e]);
  }
  for (int p = tid; p < 640 * 128; p += nt) {
    int n = p >> 7, e = p & 127;
    Wcomb[p] = (n < 128) ? Wp1[n * 256 + e] : Wih[(n - 128) * 256 + e];
  }
  for (int n = tid; n < 640; n += nt)
    cbias[n] = (n < 128) ? bp1[n] : (bih[n - 128] + bhh[n - 128]);
}

// ---------------- precompute gumbel perturbations pg[j][b*6+k] -------------
__global__ void gumbel_kernel(float* __restrict__ pg) {
  int idx = blockIdx.x * blockDim.x + threadIdx.x;
  if (idx >= NSTP * 192) return;
  int j = idx / 192, r = idx % 192;
  uint32_t a0, a1, y0, y1;
  tf2x32(0u, 42u, 0u, (uint32_t)j, a0, a1);
  tf2x32(a0, a1, 0u, (uint32_t)r, y0, y1);
  uint32_t bits = y0 ^ y1;
  float f = __uint_as_float((bits >> 9) | 0x3f800000u) - 1.0f;
  float u = fmaxf(f, 1.17549435e-38f);
  double g = -log(-log((double)u));
  pg[idx] = (float)g;
}

// ---------------- GEMM body (shared by standalone + fused) -----------------
#define TM 128
#define TN 128
#define TKK 8
template <int MODE>
__device__ __forceinline__ void gemm_body(
    int bid2, int tid, float* As, float* Bs,
    const float* __restrict__ A, const float* __restrict__ Bm, int ldb,
    const float* __restrict__ bias, float* __restrict__ C, int ldc,
    int M, int K, int relu, int NS, int c0) {
  int mB = (M + TM - 1) / TM;
  int m0 = (bid2 % mB) * TM;
  int n0 = (bid2 / mB) * TN;

  int srow = tid >> 1;
  int skq  = (tid & 1) * 4;
  int gm   = m0 + srow;
  bool mvalid = (tid < 256) && (gm < M);
  const float* Arow = A;
  if (tid < 256) {
    if (MODE == 1) {
      int gmc = mvalid ? gm : 0;
      int bb = gmc / NS, cs = gmc % NS;
      Arow = A + (size_t)(bb * (LQ + 2) + c0 + cs + 2) * EE;
    } else {
      Arow = A + (size_t)(mvalid ? gm : 0) * K;
    }
  }
  const float* Brow = Bm + (size_t)(n0 + srow) * ldb;

  float acc[8][8] = {};
  int tm = (tid >> 4) * 8;
  int tn = (tid & 15) * 8;

  for (int k0 = 0; k0 < K; k0 += TKK) {
    float4 av = make_float4(0.f, 0.f, 0.f, 0.f), bv = av;
    if (tid < 256) {
      if (mvalid) av = *(const float4*)(Arow + k0 + skq);
      bv = *(const float4*)(Brow + k0 + skq);
    }
    __syncthreads();
    if (tid < 256) {
      As[(skq + 0) * 132 + srow] = av.x; As[(skq + 1) * 132 + srow] = av.y;
      As[(skq + 2) * 132 + srow] = av.z; As[(skq + 3) * 132 + srow] = av.w;
      Bs[(skq + 0) * 132 + srow] = bv.x; Bs[(skq + 1) * 132 + srow] = bv.y;
      Bs[(skq + 2) * 132 + srow] = bv.z; Bs[(skq + 3) * 132 + srow] = bv.w;
    }
    __syncthreads();
    if (tid < 256) {
#pragma unroll
      for (int kk = 0; kk < TKK; kk++) {
        float4 a0 = *(const float4*)&As[kk * 132 + tm];
        float4 a1 = *(const float4*)&As[kk * 132 + tm + 4];
        float4 b0 = *(const float4*)&Bs[kk * 132 + tn];
        float4 b1 = *(const float4*)&Bs[kk * 132 + tn + 4];
        float aa[8] = {a0.x, a0.y, a0.z, a0.w, a1.x, a1.y, a1.z, a1.w};
        float bb2[8] = {b0.x, b0.y, b0.z, b0.w, b1.x, b1.y, b1.z, b1.w};
#pragma unroll
        for (int i = 0; i < 8; i++)
#pragma unroll
          for (int jx = 0; jx < 8; jx++) acc[i][jx] += aa[i] * bb2[jx];
      }
    }
  }
  if (tid < 256) {
#pragma unroll
    for (int i = 0; i < 8; i++) {
      int gm2 = m0 + tm + i;
      if (gm2 >= M) break;
#pragma unroll
      for (int jx = 0; jx < 8; jx++) {
        int gn = n0 + tn + jx;
        float v = acc[i][jx] + bias[gn];
        if (relu) v = fmaxf(v, 0.f);
        C[(size_t)gm2 * ldc + gn] = v;
      }
    }
  }
}

template <int MODE>
__global__ __launch_bounds__(256) void gemm_kernel(
    const float* __restrict__ A, const float* __restrict__ Bm, int ldb,
    const float* __restrict__ bias, float* __restrict__ C, int ldc,
    int M, int K, int relu, int NS, int c0) {
  __shared__ float smg[2 * 8 * 132];
  gemm_body<MODE>(blockIdx.x, threadIdx.x, smg, smg + 8 * 132,
                  A, Bm, ldb, bias, C, ldc, M, K, relu, NS, c0);
}

// bf16 row-dot term (tree identical to R14)
#define ACC4(acc, ua, ub, hvv)                                            \
  acc += bfl(ua) * (hvv).x + bfh(ua) * (hvv).y + bfl(ub) * (hvv).z +      \
         bfh(ub) * (hvv).w;

// ---------------- fused pipeline kernel ------------------------------------
__global__ __launch_bounds__(512, 2) void pipe_kernel(
    const float* __restrict__ exfS, const float* __restrict__ pg,
    const int* __restrict__ mask, const int* __restrict__ length,
    const unsigned short* __restrict__ Wp1H, const float* __restrict__ Wp2,
    const float* __restrict__ bp2, const unsigned short* __restrict__ WhcH,
    float* __restrict__ state, float* __restrict__ out,
    int c0, int NS, int init,
    const float* __restrict__ cfB, float* __restrict__ exfB,
    const float* __restrict__ Wcomb, const float* __restrict__ cbias,
    int M6n, int nbG2,
    const float* __restrict__ memory, const float* __restrict__ W1,
    const float* __restrict__ b1, float* __restrict__ cfC,
    int McfN, int NS1, int c01) {
  __shared__ __align__(16) char smem[kSmem];
  const int bidx = blockIdx.x;
  const int tid = threadIdx.x;

  if (bidx >= 32) {
    float* As = (float*)smem;
    float* Bs = As + 8 * 132;
    if (bidx < 32 + nbG2) {
      gemm_body<0>(bidx - 32, tid, As, Bs, cfB, Wcomb, 128, cbias, exfB, 640,
                   M6n, 128, 0, 0, 0);
    } else {
      gemm_body<1>(bidx - 32 - nbG2, tid, As, Bs, memory, W1, 256, b1, cfC,
                   768, McfN, 256, 1, NS1, c01);
    }
    return;
  }

  // -------------------- scan body (speculative 6-candidate) ----------------
  const int b = bidx;
  const int q = tid & 3;
  const int gbh = tid >> 2;                 // hid-row (P2b) 0..127
  const int grow = (tid < 64) ? (112 + (tid >> 2)) : ((tid >> 2) - 16);

  float* EXF0  = (float*)(smem + bEXF);
  float* hhc   = (float*)(smem + bHHC);     // [6][128]
  float* h2c   = (float*)(smem + bH2C);     // [2][6][144] padded rows
  float* c2c   = (float*)(smem + bC2C);     // [2][6][128]
  float* ghh_s = (float*)(smem + bGHH);
  float* scv   = (float*)(smem + bSCV);
  float* wp2_l = (float*)(smem + bWP2);
  float* gum_l = (float*)(smem + bGUM);
  int*   msk_l = (int*)(smem + bMSK);
  int*   idxp  = (int*)(smem + bIDXP);      // [2]
  char*  idxb  = (char*)(smem + bIDXB);

  const float bp2v = bp2[0];
  const int len_b = length[b];

  // bf16 weight row pointers
  const uint4* wS = (const uint4*)(Wp1H + (size_t)gbh * 128 + q * 32);
  const uint4* wA0 = (const uint4*)(WhcH + (size_t)grow * 128 + q * 32);
  const uint4* wA1 = (const uint4*)(WhcH + ((size_t)grow + 128) * 128 + q * 32);
  const uint4* wA2 = (const uint4*)(WhcH + ((size_t)grow + 256) * 128 + q * 32);
  const uint4* wA3 = (const uint4*)(WhcH + ((size_t)grow + 384) * 128 + q * 32);

  float lp_r = 0.f;
  // seed: h2c[buf1][k0], c2c[buf1][k0], idxp[1]=0
  if (tid < 128) {
    float hs = init ? 0.f : state[b * 128 + tid];
    float cs0 = init ? 0.f : state[4096 + b * 128 + tid];
    h2c[864 + (tid >> 5) * 36 + (tid & 31)] = hs;   // buf1, k=0
    c2c[768 + tid] = cs0;                           // buf1, k=0
    wp2_l[tid] = Wp2[tid];
  }
  if (tid == 0) {
    idxp[1] = 0;
    lp_r = init ? 0.f : state[8192 + b];
  }
  bar_lds();

  // seed hhc[k=0] = Wp1part · h_seed (tree = R14 hid tree)
  {
    const float4* hp4 = (const float4*)(h2c + 864 + q * 36);
    float4 hv[8];
#pragma unroll
    for (int i = 0; i < 8; i++) hv[i] = hp4[i];
    float hidp = 0.f;
#pragma unroll
    for (int j = 0; j < 4; j++) {
      uint4 u = wS[j];
      ACC4(hidp, u.x, u.y, hv[2 * j]);
      ACC4(hidp, u.z, u.w, hv[2 * j + 1]);
    }
    hidp += __shfl_xor(hidp, 1); hidp += __shfl_xor(hidp, 2);
    if (q == 0) hhc[gbh] = hidp;
  }

  // prologue: stage step 0 EXF; prefetch step 1 into regs (R12 pattern)
  float4 pf0, pf1, pf2;
  float pfg = 0.f; int pfm = 0;
  {
    const float4* e0 = (const float4*)(exfS + (size_t)b * NS * 3840);
    ((float4*)EXF0)[tid] = e0[tid];
    if (tid < 448) ((float4*)EXF0)[512 + tid] = e0[512 + tid];
    if (tid < 6) {
      gum_l[tid] = pg[(size_t)c0 * 192 + b * 6 + tid];
      msk_l[tid] = mask[((size_t)b * LQ + c0 + 1) * 6 + tid];
    }
    int cs1 = (NS > 1) ? 1 : 0;
    const float4* e1 = (const float4*)(exfS + ((size_t)b * NS + cs1) * 3840);
    if (tid >= 64) {
      int i0 = tid - 64;
      pf0 = e1[i0];
      pf1 = e1[448 + i0];
      if (tid < 128) pf2 = e1[896 + i0];
    }
    if (tid >= 384 && tid < 390)
      pfg = pg[(size_t)(c0 + cs1) * 192 + b * 6 + (tid - 384)];
    if (tid >= 390 && tid < 396)
      pfm = mask[((size_t)b * LQ + c0 + cs1 + 1) * 6 + (tid - 390)];
  }
  bar_lds();

  for (int cs = 0; cs < NS; ++cs) {
    const int buf = cs & 1;
    const int prv = buf ^ 1;
    float* EXFb = EXF0 + buf * 3840;
    float* EXFn = EXF0 + prv * 3840;
    const int ip = idxp[prv];
    const float* hrow = h2c + prv * 864 + ip * 144;

    // ---- P1: wave0 sample (+tail ghh); waves1-7 ghh + park + prefetch
    if (tid < 64) {
      const int k = tid >> 3, r = tid & 7;
      float s = 0.f;
      if (k < 6) {
        const float* pb = &EXFb[k * 640 + r * 16];
        const float* hb = &hhc[ip * 128 + r * 16];
        const float* wb = &wp2_l[r * 16];
#pragma unroll
        for (int ii = 0; ii < 4; ii++) {
          float4 p = *(const float4*)(pb + ii * 4);
          float4 hh = *(const float4*)(hb + ii * 4);
          float4 w = *(const float4*)(wb + ii * 4);
          s += fmaxf(p.x + hh.x, 0.f) * w.x + fmaxf(p.y + hh.y, 0.f) * w.y +
               fmaxf(p.z + hh.z, 0.f) * w.z + fmaxf(p.w + hh.w, 0.f) * w.w;
        }
      }
      s += __shfl_xor(s, 1);
      s += __shfl_xor(s, 2);
      s += __shfl_xor(s, 4);
      if (k < 6 && r == 0) scv[k] = fmaxf(s + bp2v, 0.f);
      asm volatile("s_waitcnt lgkmcnt(0)" ::: "memory");
      if (tid == 0) {
        float best = -3.4e38f, mx = -1e9f, libest = -1e9f, ssum;
        int bi = 0;
        float lgv[6];
#pragma unroll
        for (int k2 = 0; k2 < 6; k2++) {
          float lg = msk_l[buf * 8 + k2] ? scv[k2] : -1e9f;
          float pt = gum_l[buf * 8 + k2] + lg;
          if (pt > best) { best = pt; bi = k2; libest = lg; }
          mx = fmaxf(mx, lg);
          lgv[k2] = lg;
        }
        ssum = 0.f;
#pragma unroll
        for (int k2 = 0; k2 < 6; k2++) ssum += __expf(lgv[k2] - mx);
        float logp = libest - mx - __logf(ssum);
        if (len_b > c0 + cs + 1) lp_r += logp;
        idxp[buf] = bi;
        idxb[cs] = (char)bi;
      }
      // tail ghh rows (grow = 112..127), tree = R14
      {
        const float4* hp4 = (const float4*)(hrow + q * 36);
        float4 hv[8];
#pragma unroll
        for (int i = 0; i < 8; i++) hv[i] = hp4[i];
        float p0 = 0.f, p1 = 0.f, p2 = 0.f, p3 = 0.f;
#pragma unroll
        for (int j = 0; j < 4; j++) {
          uint4 u = wA0[j];
          ACC4(p0, u.x, u.y, hv[2 * j]);
          ACC4(p0, u.z, u.w, hv[2 * j + 1]);
        }
#pragma unroll
        for (int j = 0; j < 4; j++) {
          uint4 u = wA1[j];
          ACC4(p1, u.x, u.y, hv[2 * j]);
          ACC4(p1, u.z, u.w, hv[2 * j + 1]);
        }
#pragma unroll
        for (int j = 0; j < 4; j++) {
          uint4 u = wA2[j];
          ACC4(p2, u.x, u.y, hv[2 * j]);
          ACC4(p2, u.z, u.w, hv[2 * j + 1]);
        }
#pragma unroll
        for (int j = 0; j < 4; j++) {
          uint4 u = wA3[j];
          ACC4(p3, u.x, u.y, hv[2 * j]);
          ACC4(p3, u.z, u.w, hv[2 * j + 1]);
        }
        p0 += __shfl_xor(p0, 1); p0 += __shfl_xor(p0, 2);
        p1 += __shfl_xor(p1, 1); p1 += __shfl_xor(p1, 2);
        p2 += __shfl_xor(p2, 1); p2 += __shfl_xor(p2, 2);
        p3 += __shfl_xor(p3, 1); p3 += __shfl_xor(p3, 2);
        if (q == 0) {
          ghh_s[grow] = p0; ghh_s[128 + grow] = p1;
          ghh_s[256 + grow] = p2; ghh_s[384 + grow] = p3;
        }
      }
    } else {
      int i0 = tid - 64;
      // park prefetched step data
      ((float4*)EXFn)[i0] = pf0;
      ((float4*)EXFn)[448 + i0] = pf1;
      if (tid < 128) ((float4*)EXFn)[896 + i0] = pf2;
      if (tid >= 384 && tid < 390) gum_l[prv * 8 + tid - 384] = pfg;
      if (tid >= 390 && tid < 396) msk_l[prv * 8 + tid - 390] = pfm;
      // issue next prefetch
      int csp = (cs + 2 < NS) ? cs + 2 : NS - 1;
      const float4* en = (const float4*)(exfS + ((size_t)b * NS + csp) * 3840);
      pf0 = en[i0];
      pf1 = en[448 + i0];
      if (tid < 128) pf2 = en[896 + i0];
      if (tid >= 384 && tid < 390)
        pfg = pg[(size_t)(c0 + csp) * 192 + b * 6 + (tid - 384)];
      if (tid >= 390 && tid < 396)
        pfm = mask[((size_t)b * LQ + c0 + csp + 1) * 6 + (tid - 390)];
      // main ghh rows (grow = 0..111), tree = R14
      const float4* hp4 = (const float4*)(hrow + q * 36);
      float4 hv[8];
#pragma unroll
      for (int i = 0; i < 8; i++) hv[i] = hp4[i];
      float p0 = 0.f, p1 = 0.f, p2 = 0.f, p3 = 0.f;
#pragma unroll
      for (int j = 0; j < 4; j++) {
        uint4 u = wA0[j];
        ACC4(p0, u.x, u.y, hv[2 * j]);
        ACC4(p0, u.z, u.w, hv[2 * j + 1]);
      }
#pragma unroll
      for (int j = 0; j < 4; j++) {
        uint4 u = wA1[j];
        ACC4(p1, u.x, u.y, hv[2 * j]);
        ACC4(p1, u.z, u.w, hv[2 * j + 1]);
      }
#pragma unroll
      for (int j = 0; j < 4; j++) {
        uint4 u = wA2[j];
        ACC4(p2, u.x, u.y, hv[2 * j]);
        ACC4(p2, u.z, u.w, hv[2 * j + 1]);
      }
#pragma unroll
      for (int j = 0; j < 4; j++) {
        uint4 u = wA3[j];
        ACC4(p3, u.x, u.y, hv[2 * j]);
        ACC4(p3, u.z, u.w, hv[2 * j + 1]);
      }
      p0 += __shfl_xor(p0, 1); p0 += __shfl_xor(p0, 2);
      p1 += __shfl_xor(p1, 1); p1 += __shfl_xor(p1, 2);
      p2 += __shfl_xor(p2, 1); p2 += __shfl_xor(p2, 2);
      p3 += __shfl_xor(p3, 1); p3 += __shfl_xor(p3, 2);
      if (q == 0) {
        ghh_s[grow] = p0; ghh_s[128 + grow] = p1;
        ghh_s[256 + grow] = p2; ghh_s[384 + grow] = p3;
      }
    }
    bar_lds();

    // ---- P2a: candidate LSTM pointwise for all 6 k (formulas = R14 D)
    {
      float* h2o = h2c + buf * 864;
      float* c2o = c2c + buf * 768;
      const float* c2i = c2c + prv * 768 + ip * 128;
#pragma unroll
      for (int pass = 0; pass < 2; ++pass) {
        int s = pass * 512 + tid;
        if (s < 768) {
          int k = s >> 7, e = s & 127;
          int base = k * 640 + 128 + e;
          float iv = EXFb[base] + ghh_s[e];
          float fv = EXFb[base + 128] + ghh_s[128 + e];
          float gg = EXFb[base + 256] + ghh_s[256 + e];
          float ov = EXFb[base + 384] + ghh_s[384 + e];
          float cp = c2i[e];
          float c2v = sigm(fv) * cp + sigm(iv) * tanhf(gg);
          float h2v = sigm(ov) * tanhf(c2v);
          c2o[k * 128 + e] = c2v;
          h2o[k * 144 + (e >> 5) * 36 + (e & 31)] = h2v;
        }
      }
    }
    bar_lds();

    // ---- P2b: hhc[k] = Wp1part · h2c[k] for all 6 k (tree = R14 hid)
    {
      uint4 wrow[4];
#pragma unroll
      for (int j = 0; j < 4; j++) wrow[j] = wS[j];
      const float* h2i = h2c + buf * 864;
#pragma unroll
      for (int k = 0; k < 6; k++) {
        const float4* hp4 = (const float4*)(h2i + k * 144 + q * 36);
        float4 hv[8];
#pragma unroll
        for (int i = 0; i < 8; i++) hv[i] = hp4[i];
        float hidp = 0.f;
#pragma unroll
        for (int j = 0; j < 4; j++) {
          uint4 u = wrow[j];
          ACC4(hidp, u.x, u.y, hv[2 * j]);
          ACC4(hidp, u.z, u.w, hv[2 * j + 1]);
        }
        hidp += __shfl_xor(hidp, 1); hidp += __shfl_xor(hidp, 2);
        if (q == 0) hhc[k * 128 + gbh] = hidp;
      }
    }
    bar_lds();
  }

  // ---- epilogue: select final state
  {
    int fb = (NS - 1) & 1;
    int fi = idxp[fb];
    if (tid < 128) {
      state[b * 128 + tid] =
          h2c[fb * 864 + fi * 144 + (tid >> 5) * 36 + (tid & 31)];
      state[4096 + b * 128 + tid] = c2c[fb * 768 + fi * 128 + tid];
    }
    if (tid == 0) {
      state[8192 + b] = lp_r;
      out[b] = lp_r;
    }
    for (int i = tid; i < NS; i += 512)
      out[32 + (size_t)(c0 + i) * 32 + b] = (float)idxb[i];
  }
}

__global__ void sentinel_kernel(float* out, int n, float val) {
  int i = blockIdx.x * blockDim.x + threadIdx.x;
  if (i < n) out[i] = val;
}

// ---------------------------------------------------------------------------
extern "C" void kernel_launch(void* const* d_in, const int* in_sizes, int n_in,
                              void* d_out, int out_size, void* d_ws,
                              size_t ws_size, hipStream_t stream) {
  const float* memory = (const float*)d_in[0];
  const int* mask = (const int*)d_in[1];     // bool delivered as int32
  const int* length = (const int*)d_in[2];
  const float* W1  = (const float*)d_in[3];
  const float* b1  = (const float*)d_in[4];
  const float* Wp1 = (const float*)d_in[5];
  const float* bp1 = (const float*)d_in[6];
  const float* Wp2 = (const float*)d_in[7];
  const float* bp2 = (const float*)d_in[8];
  const float* Wih = (const float*)d_in[9];
  const float* Whh = (const float*)d_in[10];
  const float* bih = (const float*)d_in[11];
  const float* bhh = (const float*)d_in[12];
  float* out = (float*)d_out;

  char* ws = (char*)d_ws;
  const size_t o_wcomb = 0;                    // 327680
  const size_t o_cbias = 327680;               // 2560
  const size_t o_state = 330240;               // -> pad to 367104
  const size_t o_pg    = 367104;               // 1572096 -> ends 1939200
  const size_t o_whcH  = 1939200;              // 131072
  const size_t o_wp1H  = 2070272;              // 32768
  const size_t o_buf   = 2103040;

  const size_t per_cs = 2ull * 32 * (768 + 3840) * 4;  // 1179648
  long long usable = (long long)ws_size - (long long)o_buf;
  int CS = (usable > 0) ? (int)(usable / (long long)per_cs) : 0;
  if (CS > CSMAX) CS = CSMAX;
  if (CS > NSTP) CS = NSTP;
  if (CS < 1) {
    float val = -100000.0f - (float)(ws_size >> 20);
    sentinel_kernel<<<(out_size + 255) / 256, 256, 0, stream>>>(out, out_size, val);
    return;
  }

  float* Wcomb = (float*)(ws + o_wcomb);
  float* cbias = (float*)(ws + o_cbias);
  float* state = (float*)(ws + o_state);
  float* pgbuf = (float*)(ws + o_pg);
  unsigned short* WhcH = (unsigned short*)(ws + o_whcH);
  unsigned short* Wp1H = (unsigned short*)(ws + o_wp1H);

  const size_t cfsz = (size_t)32 * CS * 768;
  const size_t exsz = (size_t)32 * CS * 3840;
  float* cfb[2], * exfb[2];
  cfb[0]  = (float*)(ws + o_buf);
  cfb[1]  = cfb[0] + cfsz;
  exfb[0] = cfb[1] + cfsz;
  exfb[1] = exfb[0] + exsz;

  const int nc = (NSTP + CS - 1) / CS;
  auto NSof = [&](int c) { return (c * CS + CS <= NSTP) ? CS : (NSTP - c * CS); };

  prep_kernel<<<64, 256, 0, stream>>>(Wp1, bp1, Wih, Whh, bih, bhh,
                                      Wcomb, cbias, WhcH, Wp1H);
  gumbel_kernel<<<(NSTP * 192 + 255) / 256, 256, 0, stream>>>(pgbuf);

  // prologue: cf(0), exf(0), cf(1)
  {
    int NS0 = NSof(0), Mcf0 = 32 * NS0, M60 = Mcf0 * 6;
    gemm_kernel<1><<<((Mcf0 + TM - 1) / TM) * (768 / TN), 256, 0, stream>>>(
        memory, W1, 256, b1, cfb[0], 768, Mcf0, 256, 1, NS0, 0);
    gemm_kernel<0><<<((M60 + TM - 1) / TM) * (640 / TN), 256, 0, stream>>>(
        cfb[0], Wcomb, 128, cbias, exfb[0], 640, M60, 128, 0, NS0, 0);
    if (nc > 1) {
      int NS1 = NSof(1), Mcf1 = 32 * NS1;
      gemm_kernel<1><<<((Mcf1 + TM - 1) / TM) * (768 / TN), 256, 0, stream>>>(
          memory, W1, 256, b1, cfb[1], 768, Mcf1, 256, 1, NS1, CS);
    }
  }

  for (int c = 0; c < nc; ++c) {
    int NSc = NSof(c);
    int nbG2 = 0, M6n = 0;
    if (c + 1 < nc) {
      M6n = 32 * NSof(c + 1) * 6;
      nbG2 = ((M6n + TM - 1) / TM) * (640 / TN);
    }
    int nbG1 = 0, McfN = 0, NS1 = 1, c01 = 0;
    if (c + 2 < nc) {
      NS1 = NSof(c + 2);
      McfN = 32 * NS1;
      c01 = (c + 2) * CS;
      nbG1 = ((McfN + TM - 1) / TM) * (768 / TN);
    }
    pipe_kernel<<<32 + nbG2 + nbG1, 512, 0, stream>>>(
        exfb[c & 1], pgbuf, mask, length, Wp1H, Wp2, bp2, WhcH, state, out,
        c * CS, NSc, (c == 0) ? 1 : 0,
        cfb[(c + 1) & 1], exfb[(c + 1) & 1], Wcomb, cbias, M6n, nbG2,
        memory, W1, b1, cfb[(c + 2) & 1], McfN, NS1, c01);
  }
}

// Round 16
// 4668.310 us; speedup vs baseline: 2.4902x; 2.4902x over previous
//
#include <hip/hip_runtime.h>
#include <hip/hip_bf16.h>
#include <cstdint>

// ---------------------------------------------------------------------------
// B=32, L=2048, E=256, H=128, C=128. Scan steps j=0..2046 (t=j+1).
// R16: R14 (verified 462us/dispatch) + barrier merge: LSTM moved into the
// sampling phase on wave 0 (c-state in LDS), 3 barriers/step -> 2.
// R15's speculative 6-candidate variant was 2.9x slower (6x critical work);
// reverted. All arithmetic expressions verbatim R14 (absmax 0.0 lineage).
// ---------------------------------------------------------------------------
static constexpr int BB   = 32;
static constexpr int LQ   = 2048;
static constexpr int NSTP = 2047;
static constexpr int EE   = 256;

// scan LDS byte offsets within the static union
static constexpr int bEXF  = 0;        // 2*3840*4 = 30720
static constexpr int bHP   = 30720;    // 144*4
static constexpr int bHH   = 31296;    // 128*4
static constexpr int bGHH  = 31808;    // 512*4
static constexpr int bSCV  = 33856;    // 32
static constexpr int bWP2  = 33888;    // 512
static constexpr int bGUM  = 34400;    // 64
static constexpr int bMSK  = 34464;    // 64
static constexpr int bCLD  = 34528;    // 128*4 = 512 (c-state)
static constexpr int bIDXB = 35040;    // 448
static constexpr int kSmem = 35488;
static constexpr int CSMAX = 448;

__device__ __forceinline__ void bar_lds() {
  asm volatile("s_waitcnt lgkmcnt(0)\n\ts_barrier" ::: "memory");
}

__device__ __forceinline__ float bfl(uint32_t u) {
  return __uint_as_float(u << 16);
}
__device__ __forceinline__ float bfh(uint32_t u) {
  return __uint_as_float(u & 0xffff0000u);
}
__device__ __forceinline__ unsigned short f2bf(float f) {
  uint32_t u = __float_as_uint(f);
  uint32_t r = (u + 0x7fffu + ((u >> 16) & 1u)) >> 16;
  return (unsigned short)r;
}

// ---------------- Threefry-2x32 (JAX-compatible, verified R3-R15) ----------
__device__ __forceinline__ uint32_t rotl32(uint32_t x, int d) {
  return (x << d) | (x >> (32 - d));
}
__device__ __forceinline__ void tf2x32(uint32_t k0, uint32_t k1,
                                       uint32_t x0, uint32_t x1,
                                       uint32_t& o0, uint32_t& o1) {
  uint32_t ks2 = k0 ^ k1 ^ 0x1BD11BDAu;
  x0 += k0; x1 += k1;
  x0+=x1; x1=rotl32(x1,13); x1^=x0;  x0+=x1; x1=rotl32(x1,15); x1^=x0;
  x0+=x1; x1=rotl32(x1,26); x1^=x0;  x0+=x1; x1=rotl32(x1, 6); x1^=x0;
  x0+=k1; x1+=ks2+1u;
  x0+=x1; x1=rotl32(x1,17); x1^=x0;  x0+=x1; x1=rotl32(x1,29); x1^=x0;
  x0+=x1; x1=rotl32(x1,16); x1^=x0;  x0+=x1; x1=rotl32(x1,24); x1^=x0;
  x0+=ks2; x1+=k0+2u;
  x0+=x1; x1=rotl32(x1,13); x1^=x0;  x0+=x1; x1=rotl32(x1,15); x1^=x0;
  x0+=x1; x1=rotl32(x1,26); x1^=x0;  x0+=x1; x1=rotl32(x1, 6); x1^=x0;
  x0+=k0; x1+=k1+3u;
  x0+=x1; x1=rotl32(x1,17); x1^=x0;  x0+=x1; x1=rotl32(x1,29); x1^=x0;
  x0+=x1; x1=rotl32(x1,16); x1^=x0;  x0+=x1; x1=rotl32(x1,24); x1^=x0;
  x0+=k1; x1+=ks2+4u;
  x0+=x1; x1=rotl32(x1,13); x1^=x0;  x0+=x1; x1=rotl32(x1,15); x1^=x0;
  x0+=x1; x1=rotl32(x1,26); x1^=x0;  x0+=x1; x1=rotl32(x1, 6); x1^=x0;
  x0+=ks2; x1+=k0+5u;
  o0 = x0; o1 = x1;
}

__device__ __forceinline__ float sigm(float x) { return 1.0f / (1.0f + expf(-x)); }

// ---------------- prep: bf16 weights, Wcomb/cbias --------------------------
__global__ void prep_kernel(const float* __restrict__ Wp1,
                            const float* __restrict__ bp1,
                            const float* __restrict__ Wih,
                            const float* __restrict__ Whh,
                            const float* __restrict__ bih,
                            const float* __restrict__ bhh,
                            float* __restrict__ Wcomb,
                            float* __restrict__ cbias,
                            unsigned short* __restrict__ WhcH,
                            unsigned short* __restrict__ Wp1H) {
  int tid = blockIdx.x * blockDim.x + threadIdx.x;
  int nt  = gridDim.x * blockDim.x;
  for (int p = tid; p < 512 * 128; p += nt) {
    int g = p >> 7, e = p & 127;
    WhcH[p] = f2bf(Wih[g * 256 + 128 + e] + Whh[p]);
  }
  for (int p = tid; p < 128 * 128; p += nt) {
    int r = p >> 7, e = p & 127;
    Wp1H[p] = f2bf(Wp1[r * 256 + 128 + e]);
  }
  for (int p = tid; p < 640 * 128; p += nt) {
    int n = p >> 7, e = p & 127;
    Wcomb[p] = (n < 128) ? Wp1[n * 256 + e] : Wih[(n - 128) * 256 + e];
  }
  for (int n = tid; n < 640; n += nt)
    cbias[n] = (n < 128) ? bp1[n] : (bih[n - 128] + bhh[n - 128]);
}

// ---------------- precompute gumbel perturbations pg[j][b*6+k] -------------
__global__ void gumbel_kernel(float* __restrict__ pg) {
  int idx = blockIdx.x * blockDim.x + threadIdx.x;
  if (idx >= NSTP * 192) return;
  int j = idx / 192, r = idx % 192;
  uint32_t a0, a1, y0, y1;
  tf2x32(0u, 42u, 0u, (uint32_t)j, a0, a1);
  tf2x32(a0, a1, 0u, (uint32_t)r, y0, y1);
  uint32_t bits = y0 ^ y1;
  float f = __uint_as_float((bits >> 9) | 0x3f800000u) - 1.0f;
  float u = fmaxf(f, 1.17549435e-38f);
  double g = -log(-log((double)u));
  pg[idx] = (float)g;
}

// ---------------- GEMM body (shared by standalone + fused) -----------------
#define TM 128
#define TN 128
#define TKK 8
template <int MODE>
__device__ __forceinline__ void gemm_body(
    int bid2, int tid, float* As, float* Bs,
    const float* __restrict__ A, const float* __restrict__ Bm, int ldb,
    const float* __restrict__ bias, float* __restrict__ C, int ldc,
    int M, int K, int relu, int NS, int c0) {
  int mB = (M + TM - 1) / TM;
  int m0 = (bid2 % mB) * TM;
  int n0 = (bid2 / mB) * TN;

  int srow = tid >> 1;
  int skq  = (tid & 1) * 4;
  int gm   = m0 + srow;
  bool mvalid = (tid < 256) && (gm < M);
  const float* Arow = A;
  if (tid < 256) {
    if (MODE == 1) {
      int gmc = mvalid ? gm : 0;
      int bb = gmc / NS, cs = gmc % NS;
      Arow = A + (size_t)(bb * (LQ + 2) + c0 + cs + 2) * EE;
    } else {
      Arow = A + (size_t)(mvalid ? gm : 0) * K;
    }
  }
  const float* Brow = Bm + (size_t)(n0 + srow) * ldb;

  float acc[8][8] = {};
  int tm = (tid >> 4) * 8;
  int tn = (tid & 15) * 8;

  for (int k0 = 0; k0 < K; k0 += TKK) {
    float4 av = make_float4(0.f, 0.f, 0.f, 0.f), bv = av;
    if (tid < 256) {
      if (mvalid) av = *(const float4*)(Arow + k0 + skq);
      bv = *(const float4*)(Brow + k0 + skq);
    }
    __syncthreads();
    if (tid < 256) {
      As[(skq + 0) * 132 + srow] = av.x; As[(skq + 1) * 132 + srow] = av.y;
      As[(skq + 2) * 132 + srow] = av.z; As[(skq + 3) * 132 + srow] = av.w;
      Bs[(skq + 0) * 132 + srow] = bv.x; Bs[(skq + 1) * 132 + srow] = bv.y;
      Bs[(skq + 2) * 132 + srow] = bv.z; Bs[(skq + 3) * 132 + srow] = bv.w;
    }
    __syncthreads();
    if (tid < 256) {
#pragma unroll
      for (int kk = 0; kk < TKK; kk++) {
        float4 a0 = *(const float4*)&As[kk * 132 + tm];
        float4 a1 = *(const float4*)&As[kk * 132 + tm + 4];
        float4 b0 = *(const float4*)&Bs[kk * 132 + tn];
        float4 b1 = *(const float4*)&Bs[kk * 132 + tn + 4];
        float aa[8] = {a0.x, a0.y, a0.z, a0.w, a1.x, a1.y, a1.z, a1.w};
        float bb2[8] = {b0.x, b0.y, b0.z, b0.w, b1.x, b1.y, b1.z, b1.w};
#pragma unroll
        for (int i = 0; i < 8; i++)
#pragma unroll
          for (int jx = 0; jx < 8; jx++) acc[i][jx] += aa[i] * bb2[jx];
      }
    }
  }
  if (tid < 256) {
#pragma unroll
    for (int i = 0; i < 8; i++) {
      int gm2 = m0 + tm + i;
      if (gm2 >= M) break;
#pragma unroll
      for (int jx = 0; jx < 8; jx++) {
        int gn = n0 + tn + jx;
        float v = acc[i][jx] + bias[gn];
        if (relu) v = fmaxf(v, 0.f);
        C[(size_t)gm2 * ldc + gn] = v;
      }
    }
  }
}

template <int MODE>
__global__ __launch_bounds__(256) void gemm_kernel(
    const float* __restrict__ A, const float* __restrict__ Bm, int ldb,
    const float* __restrict__ bias, float* __restrict__ C, int ldc,
    int M, int K, int relu, int NS, int c0) {
  __shared__ float smg[2 * 8 * 132];
  gemm_body<MODE>(blockIdx.x, threadIdx.x, smg, smg + 8 * 132,
                  A, Bm, ldb, bias, C, ldc, M, K, relu, NS, c0);
}

// bf16 row-dot term (tree identical to R14)
#define ACC4(acc, ua, ub, hvv)                                            \
  acc += bfl(ua) * (hvv).x + bfh(ua) * (hvv).y + bfl(ub) * (hvv).z +      \
         bfh(ub) * (hvv).w;

// ---------------- fused pipeline kernel ------------------------------------
// blocks [0,32): scan (chunk c); [32,32+nbG2): GEMM2 (c+1); rest: GEMM1 (c+2)
__global__ __launch_bounds__(512, 2) void pipe_kernel(
    const float* __restrict__ exfS, const float* __restrict__ pg,
    const int* __restrict__ mask, const int* __restrict__ length,
    const unsigned short* __restrict__ Wp1H, const float* __restrict__ Wp2,
    const float* __restrict__ bp2, const unsigned short* __restrict__ WhcH,
    float* __restrict__ state, float* __restrict__ out,
    int c0, int NS, int init,
    const float* __restrict__ cfB, float* __restrict__ exfB,
    const float* __restrict__ Wcomb, const float* __restrict__ cbias,
    int M6n, int nbG2,
    const float* __restrict__ memory, const float* __restrict__ W1,
    const float* __restrict__ b1, float* __restrict__ cfC,
    int McfN, int NS1, int c01) {
  __shared__ __align__(16) char smem[kSmem];
  const int bidx = blockIdx.x;
  const int tid = threadIdx.x;

  if (bidx >= 32) {
    float* As = (float*)smem;
    float* Bs = As + 8 * 132;
    if (bidx < 32 + nbG2) {
      gemm_body<0>(bidx - 32, tid, As, Bs, cfB, Wcomb, 128, cbias, exfB, 640,
                   M6n, 128, 0, 0, 0);
    } else {
      gemm_body<1>(bidx - 32 - nbG2, tid, As, Bs, memory, W1, 256, b1, cfC,
                   768, McfN, 256, 1, NS1, c01);
    }
    return;
  }

  // -------------------- scan body --------------------
  const int b = bidx;
  const int q = tid & 3;
  const int gb = tid >> 2;

  float* EXF0  = (float*)(smem + bEXF);
  float* h_pad = (float*)(smem + bHP);
  float* hh_s  = (float*)(smem + bHH);
  float* ghh_s = (float*)(smem + bGHH);
  float* scv   = (float*)(smem + bSCV);
  float* wp2_l = (float*)(smem + bWP2);
  float* gum_l = (float*)(smem + bGUM);
  int*   msk_l = (int*)(smem + bMSK);
  float* c_lds = (float*)(smem + bCLD);
  char*  idxb  = (char*)(smem + bIDXB);

  const float bp2v = bp2[0];
  const int len_b = length[b];

  float lp_r = 0.f;
  if (tid < 144) h_pad[tid] = 0.f;
  if (tid < 128) {
    if (!init) h_pad[(tid >> 5) * 36 + (tid & 31)] = state[b * 128 + tid];
    c_lds[tid] = init ? 0.f : state[4096 + b * 128 + tid];
    wp2_l[tid] = Wp2[tid];
  }
  if (tid == 0) lp_r = init ? 0.f : state[8192 + b];

  float4 pf0, pf1, pf2;
  float pfg = 0.f; int pfm = 0;
  {
    const float4* e0 = (const float4*)(exfS + (size_t)b * NS * 3840);
    ((float4*)EXF0)[tid] = e0[tid];
    if (tid < 448) ((float4*)EXF0)[512 + tid] = e0[512 + tid];
    if (tid < 6) {
      gum_l[tid] = pg[(size_t)c0 * 192 + b * 6 + tid];
      msk_l[tid] = mask[((size_t)b * LQ + c0 + 1) * 6 + tid];
    }
    int cs1 = (NS > 1) ? 1 : 0;
    const float4* e1 = (const float4*)(exfS + ((size_t)b * NS + cs1) * 3840);
    if (tid >= 64) {
      int i0 = tid - 64;
      pf0 = e1[i0];
      pf1 = e1[448 + i0];
      if (tid < 128) pf2 = e1[896 + i0];
    }
    if (tid >= 384 && tid < 390)
      pfg = pg[(size_t)(c0 + cs1) * 192 + b * 6 + (tid - 384)];
    if (tid >= 390 && tid < 396)
      pfm = mask[((size_t)b * LQ + c0 + cs1 + 1) * 6 + (tid - 390)];
  }
  bar_lds();

  for (int cs = 0; cs < NS; ++cs) {
    const int buf = cs & 1;
    const int nb = buf ^ 1;
    float* EXFb = EXF0 + buf * 3840;
    float* EXFn = EXF0 + nb * 3840;

    // ---- phase A: bf16 weight streams (trees = R14)
    {
      const float4* hp4 = (const float4*)(h_pad + q * 36);
      float4 hv[8];
#pragma unroll
      for (int i = 0; i < 8; i++) hv[i] = hp4[i];

      const uint4* s0 = (const uint4*)(Wp1H + (size_t)gb * 128 + q * 32);
      const uint4* a0 = (const uint4*)(WhcH + (size_t)gb * 128 + q * 32);
      const uint4* a1 = (const uint4*)(WhcH + ((size_t)gb + 128) * 128 + q * 32);
      const uint4* a2 = (const uint4*)(WhcH + ((size_t)gb + 256) * 128 + q * 32);
      const uint4* a3 = (const uint4*)(WhcH + ((size_t)gb + 384) * 128 + q * 32);

      float hidp = 0.f, p0 = 0.f, p1 = 0.f, p2 = 0.f, p3 = 0.f;
#pragma unroll
      for (int j = 0; j < 4; j++) {
        uint4 u = s0[j];
        ACC4(hidp, u.x, u.y, hv[2 * j]);
        ACC4(hidp, u.z, u.w, hv[2 * j + 1]);
      }
#pragma unroll
      for (int j = 0; j < 4; j++) {
        uint4 u = a0[j];
        ACC4(p0, u.x, u.y, hv[2 * j]);
        ACC4(p0, u.z, u.w, hv[2 * j + 1]);
      }
#pragma unroll
      for (int j = 0; j < 4; j++) {
        uint4 u = a1[j];
        ACC4(p1, u.x, u.y, hv[2 * j]);
        ACC4(p1, u.z, u.w, hv[2 * j + 1]);
      }
#pragma unroll
      for (int j = 0; j < 4; j++) {
        uint4 u = a2[j];
        ACC4(p2, u.x, u.y, hv[2 * j]);
        ACC4(p2, u.z, u.w, hv[2 * j + 1]);
      }
#pragma unroll
      for (int j = 0; j < 4; j++) {
        uint4 u = a3[j];
        ACC4(p3, u.x, u.y, hv[2 * j]);
        ACC4(p3, u.z, u.w, hv[2 * j + 1]);
      }
      hidp += __shfl_xor(hidp, 1); hidp += __shfl_xor(hidp, 2);
      p0 += __shfl_xor(p0, 1); p0 += __shfl_xor(p0, 2);
      p1 += __shfl_xor(p1, 1); p1 += __shfl_xor(p1, 2);
      p2 += __shfl_xor(p2, 1); p2 += __shfl_xor(p2, 2);
      p3 += __shfl_xor(p3, 1); p3 += __shfl_xor(p3, 2);
      if (q == 0) {
        hh_s[gb] = hidp;
        ghh_s[gb] = p0; ghh_s[128 + gb] = p1;
        ghh_s[256 + gb] = p2; ghh_s[384 + gb] = p3;
      }
    }
    bar_lds();

    // ---- phase BC+D: wave 0 scores+samples+LSTM; waves 1-7 park & prefetch
    if (tid < 64) {
      const int k = tid >> 3, r = tid & 7;
      float s = 0.f;
      if (k < 6) {
        const float* pb = &EXFb[k * 640 + r * 16];
        const float* hb = &hh_s[r * 16];
        const float* wb = &wp2_l[r * 16];
#pragma unroll
        for (int ii = 0; ii < 4; ii++) {
          float4 p = *(const float4*)(pb + ii * 4);
          float4 hh = *(const float4*)(hb + ii * 4);
          float4 w = *(const float4*)(wb + ii * 4);
          s += fmaxf(p.x + hh.x, 0.f) * w.x + fmaxf(p.y + hh.y, 0.f) * w.y +
               fmaxf(p.z + hh.z, 0.f) * w.z + fmaxf(p.w + hh.w, 0.f) * w.w;
        }
      }
      s += __shfl_xor(s, 1);
      s += __shfl_xor(s, 2);
      s += __shfl_xor(s, 4);
      if (k < 6 && r == 0) scv[k] = fmaxf(s + bp2v, 0.f);
      asm volatile("s_waitcnt lgkmcnt(0)" ::: "memory");
      int bi_loc = 0;
      if (tid == 0) {
        float best = -3.4e38f, mx = -1e9f, libest = -1e9f, ssum;
        int bi = 0;
        float lgv[6];
#pragma unroll
        for (int k2 = 0; k2 < 6; k2++) {
          float lg = msk_l[buf * 8 + k2] ? scv[k2] : -1e9f;
          float pt = gum_l[buf * 8 + k2] + lg;
          if (pt > best) { best = pt; bi = k2; libest = lg; }
          mx = fmaxf(mx, lg);
          lgv[k2] = lg;
        }
        ssum = 0.f;
#pragma unroll
        for (int k2 = 0; k2 < 6; k2++) ssum += __expf(lgv[k2] - mx);
        float logp = libest - mx - __logf(ssum);
        if (len_b > c0 + cs + 1) lp_r += logp;
        idxb[cs] = (char)bi;
        bi_loc = bi;
      }
      const int bi_all = __shfl(bi_loc, 0);
      // LSTM pointwise (2 elems/lane; formulas = R14 phase D)
#pragma unroll
      for (int half = 0; half < 2; ++half) {
        int e = half * 64 + tid;
        int base = bi_all * 640 + 128 + e;
        float iv = EXFb[base] + ghh_s[e];
        float fv = EXFb[base + 128] + ghh_s[128 + e];
        float gg = EXFb[base + 256] + ghh_s[256 + e];
        float ov = EXFb[base + 384] + ghh_s[384 + e];
        float cp = c_lds[e];
        float c2 = sigm(fv) * cp + sigm(iv) * tanhf(gg);
        float h2 = sigm(ov) * tanhf(c2);
        c_lds[e] = c2;
        h_pad[(e >> 5) * 36 + (e & 31)] = h2;
      }
    } else {
      int i0 = tid - 64;
      ((float4*)EXFn)[i0] = pf0;
      ((float4*)EXFn)[448 + i0] = pf1;
      if (tid < 128) ((float4*)EXFn)[896 + i0] = pf2;
      if (tid >= 384 && tid < 390) gum_l[nb * 8 + tid - 384] = pfg;
      if (tid >= 390 && tid < 396) msk_l[nb * 8 + tid - 390] = pfm;
      int csp = (cs + 2 < NS) ? cs + 2 : NS - 1;
      const float4* en = (const float4*)(exfS + ((size_t)b * NS + csp) * 3840);
      pf0 = en[i0];
      pf1 = en[448 + i0];
      if (tid < 128) pf2 = en[896 + i0];
      if (tid >= 384 && tid < 390)
        pfg = pg[(size_t)(c0 + csp) * 192 + b * 6 + (tid - 384)];
      if (tid >= 390 && tid < 396)
        pfm = mask[((size_t)b * LQ + c0 + csp + 1) * 6 + (tid - 390)];
    }
    bar_lds();
  }

  if (tid < 128) {
    state[b * 128 + tid] = h_pad[(tid >> 5) * 36 + (tid & 31)];
    state[4096 + b * 128 + tid] = c_lds[tid];
  }
  if (tid == 0) {
    state[8192 + b] = lp_r;
    out[b] = lp_r;
  }
  for (int i = tid; i < NS; i += 512)
    out[32 + (size_t)(c0 + i) * 32 + b] = (float)idxb[i];
}

__global__ void sentinel_kernel(float* out, int n, float val) {
  int i = blockIdx.x * blockDim.x + threadIdx.x;
  if (i < n) out[i] = val;
}

// ---------------------------------------------------------------------------
extern "C" void kernel_launch(void* const* d_in, const int* in_sizes, int n_in,
                              void* d_out, int out_size, void* d_ws,
                              size_t ws_size, hipStream_t stream) {
  const float* memory = (const float*)d_in[0];
  const int* mask = (const int*)d_in[1];     // bool delivered as int32
  const int* length = (const int*)d_in[2];
  const float* W1  = (const float*)d_in[3];
  const float* b1  = (const float*)d_in[4];
  const float* Wp1 = (const float*)d_in[5];
  const float* bp1 = (const float*)d_in[6];
  const float* Wp2 = (const float*)d_in[7];
  const float* bp2 = (const float*)d_in[8];
  const float* Wih = (const float*)d_in[9];
  const float* Whh = (const float*)d_in[10];
  const float* bih = (const float*)d_in[11];
  const float* bhh = (const float*)d_in[12];
  float* out = (float*)d_out;

  char* ws = (char*)d_ws;
  const size_t o_wcomb = 0;                    // 327680
  const size_t o_cbias = 327680;               // 2560
  const size_t o_state = 330240;               // -> pad to 367104
  const size_t o_pg    = 367104;               // 1572096 -> ends 1939200
  const size_t o_whcH  = 1939200;              // 131072
  const size_t o_wp1H  = 2070272;              // 32768
  const size_t o_buf   = 2103040;

  const size_t per_cs = 2ull * 32 * (768 + 3840) * 4;  // 1179648
  long long usable = (long long)ws_size - (long long)o_buf;
  int CS = (usable > 0) ? (int)(usable / (long long)per_cs) : 0;
  if (CS > CSMAX) CS = CSMAX;
  if (CS > NSTP) CS = NSTP;
  if (CS < 1) {
    float val = -100000.0f - (float)(ws_size >> 20);
    sentinel_kernel<<<(out_size + 255) / 256, 256, 0, stream>>>(out, out_size, val);
    return;
  }

  float* Wcomb = (float*)(ws + o_wcomb);
  float* cbias = (float*)(ws + o_cbias);
  float* state = (float*)(ws + o_state);
  float* pgbuf = (float*)(ws + o_pg);
  unsigned short* WhcH = (unsigned short*)(ws + o_whcH);
  unsigned short* Wp1H = (unsigned short*)(ws + o_wp1H);

  const size_t cfsz = (size_t)32 * CS * 768;
  const size_t exsz = (size_t)32 * CS * 3840;
  float* cfb[2], * exfb[2];
  cfb[0]  = (float*)(ws + o_buf);
  cfb[1]  = cfb[0] + cfsz;
  exfb[0] = cfb[1] + cfsz;
  exfb[1] = exfb[0] + exsz;

  const int nc = (NSTP + CS - 1) / CS;
  auto NSof = [&](int c) { return (c * CS + CS <= NSTP) ? CS : (NSTP - c * CS); };

  prep_kernel<<<64, 256, 0, stream>>>(Wp1, bp1, Wih, Whh, bih, bhh,
                                      Wcomb, cbias, WhcH, Wp1H);
  gumbel_kernel<<<(NSTP * 192 + 255) / 256, 256, 0, stream>>>(pgbuf);

  // prologue: cf(0), exf(0), cf(1)
  {
    int NS0 = NSof(0), Mcf0 = 32 * NS0, M60 = Mcf0 * 6;
    gemm_kernel<1><<<((Mcf0 + TM - 1) / TM) * (768 / TN), 256, 0, stream>>>(
        memory, W1, 256, b1, cfb[0], 768, Mcf0, 256, 1, NS0, 0);
    gemm_kernel<0><<<((M60 + TM - 1) / TM) * (640 / TN), 256, 0, stream>>>(
        cfb[0], Wcomb, 128, cbias, exfb[0], 640, M60, 128, 0, NS0, 0);
    if (nc > 1) {
      int NS1 = NSof(1), Mcf1 = 32 * NS1;
      gemm_kernel<1><<<((Mcf1 + TM - 1) / TM) * (768 / TN), 256, 0, stream>>>(
          memory, W1, 256, b1, cfb[1], 768, Mcf1, 256, 1, NS1, CS);
    }
  }

  for (int c = 0; c < nc; ++c) {
    int NSc = NSof(c);
    int nbG2 = 0, M6n = 0;
    if (c + 1 < nc) {
      M6n = 32 * NSof(c + 1) * 6;
      nbG2 = ((M6n + TM - 1) / TM) * (640 / TN);
    }
    int nbG1 = 0, McfN = 0, NS1 = 1, c01 = 0;
    if (c + 2 < nc) {
      NS1 = NSof(c + 2);
      McfN = 32 * NS1;
      c01 = (c + 2) * CS;
      nbG1 = ((McfN + TM - 1) / TM) * (768 / TN);
    }
    pipe_kernel<<<32 + nbG2 + nbG1, 512, 0, stream>>>(
        exfb[c & 1], pgbuf, mask, length, Wp1H, Wp2, bp2, WhcH, state, out,
        c * CS, NSc, (c == 0) ? 1 : 0,
        cfb[(c + 1) & 1], exfb[(c + 1) & 1], Wcomb, cbias, M6n, nbG2,
        memory, W1, b1, cfb[(c + 2) & 1], McfN, NS1, c01);
  }
}

// Round 17
// 4170.539 us; speedup vs baseline: 2.7874x; 1.1194x over previous
//
#include <hip/hip_runtime.h>
#include <hip/hip_bf16.h>
#include <cstdint>

// ---------------------------------------------------------------------------
// B=32, L=2048, E=256, H=128, C=128. Scan steps j=0..2046 (t=j+1).
// FINAL (= R14, verified 4176us): fused pipeline (scan(c) || GEMM2(c+1) ||
// GEMM1(c+2) in one launch, 2-deep, double-buffered cf/exf) + bf16 scan
// weights. Scan is structure-bound at ~2.0us/step: R6-R16 tried register
// pinning x3, AGPR residency, phase overlap, 2x TLP, LDS weight caches x2,
// 6-way speculation, barrier merge — all regressed or null. GEMMs fully
// hidden under the scan (dispatch ~462us ~= 215 steps x 2.05us).
// ---------------------------------------------------------------------------
static constexpr int BB   = 32;
static constexpr int LQ   = 2048;
static constexpr int NSTP = 2047;
static constexpr int EE   = 256;

// scan LDS byte offsets within the 35KB union
static constexpr int bEXF  = 0;        // 2*3840*4 = 30720
static constexpr int bHP   = 30720;    // 144*4
static constexpr int bHH   = 31296;    // 128*4
static constexpr int bGHH  = 31808;    // 512*4
static constexpr int bSCV  = 33856;    // 8*4
static constexpr int bWP2  = 33888;    // 128*4
static constexpr int bGUM  = 34400;    // 16*4
static constexpr int bMSK  = 34464;    // 16*4
static constexpr int bIDX  = 34528;    // 16
static constexpr int bIDXB = 34544;    // 448
static constexpr int kSmem = 35008;
static constexpr int CSMAX = 448;

__device__ __forceinline__ void bar_lds() {
  asm volatile("s_waitcnt lgkmcnt(0)\n\ts_barrier" ::: "memory");
}

__device__ __forceinline__ float bfl(uint32_t u) {
  return __uint_as_float(u << 16);
}
__device__ __forceinline__ float bfh(uint32_t u) {
  return __uint_as_float(u & 0xffff0000u);
}
__device__ __forceinline__ unsigned short f2bf(float f) {
  uint32_t u = __float_as_uint(f);
  uint32_t r = (u + 0x7fffu + ((u >> 16) & 1u)) >> 16;
  return (unsigned short)r;
}

// ---------------- Threefry-2x32 (JAX-compatible, verified R3-R16) ----------
__device__ __forceinline__ uint32_t rotl32(uint32_t x, int d) {
  return (x << d) | (x >> (32 - d));
}
__device__ __forceinline__ void tf2x32(uint32_t k0, uint32_t k1,
                                       uint32_t x0, uint32_t x1,
                                       uint32_t& o0, uint32_t& o1) {
  uint32_t ks2 = k0 ^ k1 ^ 0x1BD11BDAu;
  x0 += k0; x1 += k1;
  x0+=x1; x1=rotl32(x1,13); x1^=x0;  x0+=x1; x1=rotl32(x1,15); x1^=x0;
  x0+=x1; x1=rotl32(x1,26); x1^=x0;  x0+=x1; x1=rotl32(x1, 6); x1^=x0;
  x0+=k1; x1+=ks2+1u;
  x0+=x1; x1=rotl32(x1,17); x1^=x0;  x0+=x1; x1=rotl32(x1,29); x1^=x0;
  x0+=x1; x1=rotl32(x1,16); x1^=x0;  x0+=x1; x1=rotl32(x1,24); x1^=x0;
  x0+=ks2; x1+=k0+2u;
  x0+=x1; x1=rotl32(x1,13); x1^=x0;  x0+=x1; x1=rotl32(x1,15); x1^=x0;
  x0+=x1; x1=rotl32(x1,26); x1^=x0;  x0+=x1; x1=rotl32(x1, 6); x1^=x0;
  x0+=k0; x1+=k1+3u;
  x0+=x1; x1=rotl32(x1,17); x1^=x0;  x0+=x1; x1=rotl32(x1,29); x1^=x0;
  x0+=x1; x1=rotl32(x1,16); x1^=x0;  x0+=x1; x1=rotl32(x1,24); x1^=x0;
  x0+=k1; x1+=ks2+4u;
  x0+=x1; x1=rotl32(x1,13); x1^=x0;  x0+=x1; x1=rotl32(x1,15); x1^=x0;
  x0+=x1; x1=rotl32(x1,26); x1^=x0;  x0+=x1; x1=rotl32(x1, 6); x1^=x0;
  x0+=ks2; x1+=k0+5u;
  o0 = x0; o1 = x1;
}

__device__ __forceinline__ float sigm(float x) { return 1.0f / (1.0f + expf(-x)); }

// ---------------- prep: Whc(+bf16), Wp1 bf16 slice, Wcomb/cbias ------------
__global__ void prep_kernel(const float* __restrict__ Wp1,
                            const float* __restrict__ bp1,
                            const float* __restrict__ Wih,
                            const float* __restrict__ Whh,
                            const float* __restrict__ bih,
                            const float* __restrict__ bhh,
                            float* __restrict__ Whc,
                            float* __restrict__ Wcomb,
                            float* __restrict__ cbias,
                            unsigned short* __restrict__ WhcH,
                            unsigned short* __restrict__ Wp1H) {
  int tid = blockIdx.x * blockDim.x + threadIdx.x;
  int nt  = gridDim.x * blockDim.x;
  for (int p = tid; p < 512 * 128; p += nt) {
    int g = p >> 7, e = p & 127;
    float v = Wih[g * 256 + 128 + e] + Whh[p];
    Whc[p] = v;
    WhcH[p] = f2bf(v);
  }
  for (int p = tid; p < 128 * 128; p += nt) {
    int r = p >> 7, e = p & 127;
    Wp1H[p] = f2bf(Wp1[r * 256 + 128 + e]);
  }
  for (int p = tid; p < 640 * 128; p += nt) {
    int n = p >> 7, e = p & 127;
    Wcomb[p] = (n < 128) ? Wp1[n * 256 + e] : Wih[(n - 128) * 256 + e];
  }
  for (int n = tid; n < 640; n += nt)
    cbias[n] = (n < 128) ? bp1[n] : (bih[n - 128] + bhh[n - 128]);
}

// ---------------- precompute gumbel perturbations pg[j][b*6+k] -------------
__global__ void gumbel_kernel(float* __restrict__ pg) {
  int idx = blockIdx.x * blockDim.x + threadIdx.x;
  if (idx >= NSTP * 192) return;
  int j = idx / 192, r = idx % 192;
  uint32_t a0, a1, y0, y1;
  tf2x32(0u, 42u, 0u, (uint32_t)j, a0, a1);
  tf2x32(a0, a1, 0u, (uint32_t)r, y0, y1);
  uint32_t bits = y0 ^ y1;
  float f = __uint_as_float((bits >> 9) | 0x3f800000u) - 1.0f;
  float u = fmaxf(f, 1.17549435e-38f);
  double g = -log(-log((double)u));
  pg[idx] = (float)g;
}

// ---------------- GEMM body (shared by standalone + fused) -----------------
#define TM 128
#define TN 128
#define TKK 8
template <int MODE>
__device__ __forceinline__ void gemm_body(
    int bid2, int tid, float* As, float* Bs,
    const float* __restrict__ A, const float* __restrict__ Bm, int ldb,
    const float* __restrict__ bias, float* __restrict__ C, int ldc,
    int M, int K, int relu, int NS, int c0) {
  int mB = (M + TM - 1) / TM;
  int m0 = (bid2 % mB) * TM;
  int n0 = (bid2 / mB) * TN;

  int srow = tid >> 1;
  int skq  = (tid & 1) * 4;
  int gm   = m0 + srow;
  bool mvalid = (tid < 256) && (gm < M);
  const float* Arow = A;
  if (tid < 256) {
    if (MODE == 1) {
      int gmc = mvalid ? gm : 0;
      int bb = gmc / NS, cs = gmc % NS;
      Arow = A + (size_t)(bb * (LQ + 2) + c0 + cs + 2) * EE;
    } else {
      Arow = A + (size_t)(mvalid ? gm : 0) * K;
    }
  }
  const float* Brow = Bm + (size_t)(n0 + srow) * ldb;

  float acc[8][8] = {};
  int tm = (tid >> 4) * 8;
  int tn = (tid & 15) * 8;

  for (int k0 = 0; k0 < K; k0 += TKK) {
    float4 av = make_float4(0.f, 0.f, 0.f, 0.f), bv = av;
    if (tid < 256) {
      if (mvalid) av = *(const float4*)(Arow + k0 + skq);
      bv = *(const float4*)(Brow + k0 + skq);
    }
    __syncthreads();
    if (tid < 256) {
      As[(skq + 0) * 132 + srow] = av.x; As[(skq + 1) * 132 + srow] = av.y;
      As[(skq + 2) * 132 + srow] = av.z; As[(skq + 3) * 132 + srow] = av.w;
      Bs[(skq + 0) * 132 + srow] = bv.x; Bs[(skq + 1) * 132 + srow] = bv.y;
      Bs[(skq + 2) * 132 + srow] = bv.z; Bs[(skq + 3) * 132 + srow] = bv.w;
    }
    __syncthreads();
    if (tid < 256) {
#pragma unroll
      for (int kk = 0; kk < TKK; kk++) {
        float4 a0 = *(const float4*)&As[kk * 132 + tm];
        float4 a1 = *(const float4*)&As[kk * 132 + tm + 4];
        float4 b0 = *(const float4*)&Bs[kk * 132 + tn];
        float4 b1 = *(const float4*)&Bs[kk * 132 + tn + 4];
        float aa[8] = {a0.x, a0.y, a0.z, a0.w, a1.x, a1.y, a1.z, a1.w};
        float bb2[8] = {b0.x, b0.y, b0.z, b0.w, b1.x, b1.y, b1.z, b1.w};
#pragma unroll
        for (int i = 0; i < 8; i++)
#pragma unroll
          for (int jx = 0; jx < 8; jx++) acc[i][jx] += aa[i] * bb2[jx];
      }
    }
  }
  if (tid < 256) {
#pragma unroll
    for (int i = 0; i < 8; i++) {
      int gm2 = m0 + tm + i;
      if (gm2 >= M) break;
#pragma unroll
      for (int jx = 0; jx < 8; jx++) {
        int gn = n0 + tn + jx;
        float v = acc[i][jx] + bias[gn];
        if (relu) v = fmaxf(v, 0.f);
        C[(size_t)gm2 * ldc + gn] = v;
      }
    }
  }
}

template <int MODE>
__global__ __launch_bounds__(256) void gemm_kernel(
    const float* __restrict__ A, const float* __restrict__ Bm, int ldb,
    const float* __restrict__ bias, float* __restrict__ C, int ldc,
    int M, int K, int relu, int NS, int c0) {
  __shared__ float smg[2 * 8 * 132];
  gemm_body<MODE>(blockIdx.x, threadIdx.x, smg, smg + 8 * 132,
                  A, Bm, ldb, bias, C, ldc, M, K, relu, NS, c0);
}

// bf16 row-dot helper: 4 uint4 per 32-weight slice; accumulation order
// matches the fp32 float4 tree (i ascending, x,y,z,w within).
#define ACC4(acc, ua, ub, hvv)                                            \
  acc += bfl(ua) * (hvv).x + bfh(ua) * (hvv).y + bfl(ub) * (hvv).z +      \
         bfh(ub) * (hvv).w;

// ---------------- fused pipeline kernel ------------------------------------
// blocks [0,32): scan (chunk c); [32,32+nbG2): GEMM2 (c+1); rest: GEMM1 (c+2)
__global__ __launch_bounds__(512, 2) void pipe_kernel(
    const float* __restrict__ exfS, const float* __restrict__ pg,
    const int* __restrict__ mask, const int* __restrict__ length,
    const unsigned short* __restrict__ Wp1H, const float* __restrict__ Wp2,
    const float* __restrict__ bp2, const unsigned short* __restrict__ WhcH,
    float* __restrict__ state, float* __restrict__ out,
    int c0, int NS, int init,
    const float* __restrict__ cfB, float* __restrict__ exfB,
    const float* __restrict__ Wcomb, const float* __restrict__ cbias,
    int M6n, int nbG2,
    const float* __restrict__ memory, const float* __restrict__ W1,
    const float* __restrict__ b1, float* __restrict__ cfC,
    int McfN, int NS1, int c01) {
  __shared__ __align__(16) char smem[kSmem];
  const int bidx = blockIdx.x;
  const int tid = threadIdx.x;

  if (bidx >= 32) {
    float* As = (float*)smem;
    float* Bs = As + 8 * 132;
    if (bidx < 32 + nbG2) {
      gemm_body<0>(bidx - 32, tid, As, Bs, cfB, Wcomb, 128, cbias, exfB, 640,
                   M6n, 128, 0, 0, 0);
    } else {
      gemm_body<1>(bidx - 32 - nbG2, tid, As, Bs, memory, W1, 256, b1, cfC,
                   768, McfN, 256, 1, NS1, c01);
    }
    return;
  }

  // -------------------- scan body --------------------
  const int b = bidx;
  const int q = tid & 3;
  const int gb = tid >> 2;

  float* EXF0  = (float*)(smem + bEXF);
  float* h_pad = (float*)(smem + bHP);
  float* hh_s  = (float*)(smem + bHH);
  float* ghh_s = (float*)(smem + bGHH);
  float* scv   = (float*)(smem + bSCV);
  float* wp2_l = (float*)(smem + bWP2);
  float* gum_l = (float*)(smem + bGUM);
  int*   msk_l = (int*)(smem + bMSK);
  int*   idxp  = (int*)(smem + bIDX);
  char*  idxb  = (char*)(smem + bIDXB);

  const float bp2v = bp2[0];
  const int len_b = length[b];

  float c_r = 0.f, lp_r = 0.f;
  if (tid < 144) h_pad[tid] = 0.f;
  if (tid < 128) {
    if (!init) h_pad[(tid >> 5) * 36 + (tid & 31)] = state[b * 128 + tid];
    c_r = init ? 0.f : state[4096 + b * 128 + tid];
    wp2_l[tid] = Wp2[tid];
  }
  if (tid == 0) lp_r = init ? 0.f : state[8192 + b];

  float4 pf0, pf1, pf2;
  float pfg = 0.f; int pfm = 0;
  {
    const float4* e0 = (const float4*)(exfS + (size_t)b * NS * 3840);
    ((float4*)EXF0)[tid] = e0[tid];
    if (tid < 448) ((float4*)EXF0)[512 + tid] = e0[512 + tid];
    if (tid < 6) {
      gum_l[tid] = pg[(size_t)c0 * 192 + b * 6 + tid];
      msk_l[tid] = mask[((size_t)b * LQ + c0 + 1) * 6 + tid];
    }
    int cs1 = (NS > 1) ? 1 : 0;
    const float4* e1 = (const float4*)(exfS + ((size_t)b * NS + cs1) * 3840);
    if (tid >= 64) {
      int i0 = tid - 64;
      pf0 = e1[i0];
      pf1 = e1[448 + i0];
      if (tid < 128) pf2 = e1[896 + i0];
    }
    if (tid >= 384 && tid < 390)
      pfg = pg[(size_t)(c0 + cs1) * 192 + b * 6 + (tid - 384)];
    if (tid >= 390 && tid < 396)
      pfm = mask[((size_t)b * LQ + c0 + cs1 + 1) * 6 + (tid - 390)];
  }
  bar_lds();

  for (int cs = 0; cs < NS; ++cs) {
    const int buf = cs & 1;
    const int nb = buf ^ 1;
    float* EXFb = EXF0 + buf * 3840;
    float* EXFn = EXF0 + nb * 3840;

    // ---- phase A: bf16 weight streams
    {
      const float4* hp4 = (const float4*)(h_pad + q * 36);
      float4 hv[8];
#pragma unroll
      for (int i = 0; i < 8; i++) hv[i] = hp4[i];

      const uint4* s0 = (const uint4*)(Wp1H + (size_t)gb * 128 + q * 32);
      const uint4* a0 = (const uint4*)(WhcH + (size_t)gb * 128 + q * 32);
      const uint4* a1 = (const uint4*)(WhcH + ((size_t)gb + 128) * 128 + q * 32);
      const uint4* a2 = (const uint4*)(WhcH + ((size_t)gb + 256) * 128 + q * 32);
      const uint4* a3 = (const uint4*)(WhcH + ((size_t)gb + 384) * 128 + q * 32);

      float hidp = 0.f, p0 = 0.f, p1 = 0.f, p2 = 0.f, p3 = 0.f;
#pragma unroll
      for (int j = 0; j < 4; j++) {
        uint4 u = s0[j];
        ACC4(hidp, u.x, u.y, hv[2 * j]);
        ACC4(hidp, u.z, u.w, hv[2 * j + 1]);
      }
#pragma unroll
      for (int j = 0; j < 4; j++) {
        uint4 u = a0[j];
        ACC4(p0, u.x, u.y, hv[2 * j]);
        ACC4(p0, u.z, u.w, hv[2 * j + 1]);
      }
#pragma unroll
      for (int j = 0; j < 4; j++) {
        uint4 u = a1[j];
        ACC4(p1, u.x, u.y, hv[2 * j]);
        ACC4(p1, u.z, u.w, hv[2 * j + 1]);
      }
#pragma unroll
      for (int j = 0; j < 4; j++) {
        uint4 u = a2[j];
        ACC4(p2, u.x, u.y, hv[2 * j]);
        ACC4(p2, u.z, u.w, hv[2 * j + 1]);
      }
#pragma unroll
      for (int j = 0; j < 4; j++) {
        uint4 u = a3[j];
        ACC4(p3, u.x, u.y, hv[2 * j]);
        ACC4(p3, u.z, u.w, hv[2 * j + 1]);
      }
      hidp += __shfl_xor(hidp, 1); hidp += __shfl_xor(hidp, 2);
      p0 += __shfl_xor(p0, 1); p0 += __shfl_xor(p0, 2);
      p1 += __shfl_xor(p1, 1); p1 += __shfl_xor(p1, 2);
      p2 += __shfl_xor(p2, 1); p2 += __shfl_xor(p2, 2);
      p3 += __shfl_xor(p3, 1); p3 += __shfl_xor(p3, 2);
      if (q == 0) {
        hh_s[gb] = hidp;
        ghh_s[gb] = p0; ghh_s[128 + gb] = p1;
        ghh_s[256 + gb] = p2; ghh_s[384 + gb] = p3;
      }
    }
    bar_lds();

    // ---- phase BC: wave 0 scores+samples; waves 1-7 park & prefetch
    if (tid < 64) {
      const int k = tid >> 3, r = tid & 7;
      float s = 0.f;
      if (k < 6) {
        const float* pb = &EXFb[k * 640 + r * 16];
        const float* hb = &hh_s[r * 16];
        const float* wb = &wp2_l[r * 16];
#pragma unroll
        for (int ii = 0; ii < 4; ii++) {
          float4 p = *(const float4*)(pb + ii * 4);
          float4 hh = *(const float4*)(hb + ii * 4);
          float4 w = *(const float4*)(wb + ii * 4);
          s += fmaxf(p.x + hh.x, 0.f) * w.x + fmaxf(p.y + hh.y, 0.f) * w.y +
               fmaxf(p.z + hh.z, 0.f) * w.z + fmaxf(p.w + hh.w, 0.f) * w.w;
        }
      }
      s += __shfl_xor(s, 1);
      s += __shfl_xor(s, 2);
      s += __shfl_xor(s, 4);
      if (k < 6 && r == 0) scv[k] = fmaxf(s + bp2v, 0.f);
      asm volatile("s_waitcnt lgkmcnt(0)" ::: "memory");
      if (tid == 0) {
        float best = -3.4e38f, mx = -1e9f, libest = -1e9f, ssum;
        int bi = 0;
        float lgv[6];
#pragma unroll
        for (int k2 = 0; k2 < 6; k2++) {
          float lg = msk_l[buf * 8 + k2] ? scv[k2] : -1e9f;
          float pt = gum_l[buf * 8 + k2] + lg;
          if (pt > best) { best = pt; bi = k2; libest = lg; }
          mx = fmaxf(mx, lg);
          lgv[k2] = lg;
        }
        ssum = 0.f;
#pragma unroll
        for (int k2 = 0; k2 < 6; k2++) ssum += __expf(lgv[k2] - mx);
        float logp = libest - mx - __logf(ssum);
        if (len_b > c0 + cs + 1) lp_r += logp;
        *idxp = bi;
        idxb[cs] = (char)bi;
      }
    } else {
      int i0 = tid - 64;
      ((float4*)EXFn)[i0] = pf0;
      ((float4*)EXFn)[448 + i0] = pf1;
      if (tid < 128) ((float4*)EXFn)[896 + i0] = pf2;
      if (tid >= 384 && tid < 390) gum_l[nb * 8 + tid - 384] = pfg;
      if (tid >= 390 && tid < 396) msk_l[nb * 8 + tid - 390] = pfm;
      int csp = (cs + 2 < NS) ? cs + 2 : NS - 1;
      const float4* en = (const float4*)(exfS + ((size_t)b * NS + csp) * 3840);
      pf0 = en[i0];
      pf1 = en[448 + i0];
      if (tid < 128) pf2 = en[896 + i0];
      if (tid >= 384 && tid < 390)
        pfg = pg[(size_t)(c0 + csp) * 192 + b * 6 + (tid - 384)];
      if (tid >= 390 && tid < 396)
        pfm = mask[((size_t)b * LQ + c0 + csp + 1) * 6 + (tid - 390)];
    }
    bar_lds();

    // ---- phase D: LSTM pointwise (tid<128)
    if (tid < 128) {
      int base = *idxp * 640 + 128 + tid;
      float iv = EXFb[base] + ghh_s[tid];
      float fv = EXFb[base + 128] + ghh_s[128 + tid];
      float gg = EXFb[base + 256] + ghh_s[256 + tid];
      float ov = EXFb[base + 384] + ghh_s[384 + tid];
      float c2 = sigm(fv) * c_r + sigm(iv) * tanhf(gg);
      float h2 = sigm(ov) * tanhf(c2);
      c_r = c2;
      h_pad[(tid >> 5) * 36 + (tid & 31)] = h2;
    }
    bar_lds();
  }

  if (tid < 128) {
    state[b * 128 + tid] = h_pad[(tid >> 5) * 36 + (tid & 31)];
    state[4096 + b * 128 + tid] = c_r;
  }
  if (tid == 0) {
    state[8192 + b] = lp_r;
    out[b] = lp_r;
  }
  for (int i = tid; i < NS; i += 512)
    out[32 + (size_t)(c0 + i) * 32 + b] = (float)idxb[i];
}

__global__ void sentinel_kernel(float* out, int n, float val) {
  int i = blockIdx.x * blockDim.x + threadIdx.x;
  if (i < n) out[i] = val;
}

// ---------------------------------------------------------------------------
extern "C" void kernel_launch(void* const* d_in, const int* in_sizes, int n_in,
                              void* d_out, int out_size, void* d_ws,
                              size_t ws_size, hipStream_t stream) {
  const float* memory = (const float*)d_in[0];
  const int* mask = (const int*)d_in[1];     // bool delivered as int32
  const int* length = (const int*)d_in[2];
  const float* W1  = (const float*)d_in[3];
  const float* b1  = (const float*)d_in[4];
  const float* Wp1 = (const float*)d_in[5];
  const float* bp1 = (const float*)d_in[6];
  const float* Wp2 = (const float*)d_in[7];
  const float* bp2 = (const float*)d_in[8];
  const float* Wih = (const float*)d_in[9];
  const float* Whh = (const float*)d_in[10];
  const float* bih = (const float*)d_in[11];
  const float* bhh = (const float*)d_in[12];
  float* out = (float*)d_out;

  char* ws = (char*)d_ws;
  const size_t o_whc   = 0;                    // 262144
  const size_t o_wcomb = 262144;               // 327680
  const size_t o_cbias = 589824;               // 2560
  const size_t o_state = 592384;               // -> pad 36864
  const size_t o_pg    = 629248;               // 1572096 -> ends 2201344
  const size_t o_whcH  = 2201344;              // 512*128*2 = 131072
  const size_t o_wp1H  = 2332416;              // 128*128*2 = 32768
  const size_t o_buf   = 2365184;

  const size_t per_cs = 2ull * 32 * (768 + 3840) * 4;  // 1179648
  long long usable = (long long)ws_size - (long long)o_buf;
  int CS = (usable > 0) ? (int)(usable / (long long)per_cs) : 0;
  if (CS > CSMAX) CS = CSMAX;
  if (CS > NSTP) CS = NSTP;
  if (CS < 1) {
    float val = -100000.0f - (float)(ws_size >> 20);
    sentinel_kernel<<<(out_size + 255) / 256, 256, 0, stream>>>(out, out_size, val);
    return;
  }

  float* Whc   = (float*)(ws + o_whc);
  float* Wcomb = (float*)(ws + o_wcomb);
  float* cbias = (float*)(ws + o_cbias);
  float* state = (float*)(ws + o_state);
  float* pgbuf = (float*)(ws + o_pg);
  unsigned short* WhcH = (unsigned short*)(ws + o_whcH);
  unsigned short* Wp1H = (unsigned short*)(ws + o_wp1H);

  const size_t cfsz = (size_t)32 * CS * 768;
  const size_t exsz = (size_t)32 * CS * 3840;
  float* cfb[2], * exfb[2];
  cfb[0]  = (float*)(ws + o_buf);
  cfb[1]  = cfb[0] + cfsz;
  exfb[0] = cfb[1] + cfsz;
  exfb[1] = exfb[0] + exsz;

  const int nc = (NSTP + CS - 1) / CS;
  auto NSof = [&](int c) { return (c * CS + CS <= NSTP) ? CS : (NSTP - c * CS); };

  prep_kernel<<<64, 256, 0, stream>>>(Wp1, bp1, Wih, Whh, bih, bhh,
                                      Whc, Wcomb, cbias, WhcH, Wp1H);
  gumbel_kernel<<<(NSTP * 192 + 255) / 256, 256, 0, stream>>>(pgbuf);

  // prologue: cf(0), exf(0), cf(1)
  {
    int NS0 = NSof(0), Mcf0 = 32 * NS0, M60 = Mcf0 * 6;
    gemm_kernel<1><<<((Mcf0 + TM - 1) / TM) * (768 / TN), 256, 0, stream>>>(
        memory, W1, 256, b1, cfb[0], 768, Mcf0, 256, 1, NS0, 0);
    gemm_kernel<0><<<((M60 + TM - 1) / TM) * (640 / TN), 256, 0, stream>>>(
        cfb[0], Wcomb, 128, cbias, exfb[0], 640, M60, 128, 0, NS0, 0);
    if (nc > 1) {
      int NS1 = NSof(1), Mcf1 = 32 * NS1;
      gemm_kernel<1><<<((Mcf1 + TM - 1) / TM) * (768 / TN), 256, 0, stream>>>(
          memory, W1, 256, b1, cfb[1], 768, Mcf1, 256, 1, NS1, CS);
    }
  }

  for (int c = 0; c < nc; ++c) {
    int NSc = NSof(c);
    int nbG2 = 0, M6n = 0;
    if (c + 1 < nc) {
      M6n = 32 * NSof(c + 1) * 6;
      nbG2 = ((M6n + TM - 1) / TM) * (640 / TN);
    }
    int nbG1 = 0, McfN = 0, NS1 = 1, c01 = 0;
    if (c + 2 < nc) {
      NS1 = NSof(c + 2);
      McfN = 32 * NS1;
      c01 = (c + 2) * CS;
      nbG1 = ((McfN + TM - 1) / TM) * (768 / TN);
    }
    pipe_kernel<<<32 + nbG2 + nbG1, 512, 0, stream>>>(
        exfb[c & 1], pgbuf, mask, length, Wp1H, Wp2, bp2, WhcH, state, out,
        c * CS, NSc, (c == 0) ? 1 : 0,
        cfb[(c + 1) & 1], exfb[(c + 1) & 1], Wcomb, cbias, M6n, nbG2,
        memory, W1, b1, cfb[(c + 2) & 1], McfN, NS1, c01);
  }
}